// Round 1
// 203.204 us; speedup vs baseline: 1.0695x; 1.0695x over previous
//
#include <hip/hip_runtime.h>

#define BT 32
#define CH 64
#define HS 56
#define WS 56
#define HH 28
#define WH 28

// ---------------- filter constants (exact reference values) ----------------
namespace {
constexpr float ISQ2 = 0.70710678118654752440f;
constexpr float F_H0[13] = {-0.0017578125f, 0.0f, 0.022265625f, -0.046875f,
    -0.0482421875f, 0.296875f, 0.55546875f, 0.296875f, -0.0482421875f,
    -0.046875f, 0.022265625f, 0.0f, -0.0017578125f};
constexpr float F_H1[19] = {-7.0626e-05f, 0.0f, 0.00134189f, -0.00188341f,
    -0.0071566f, 0.023856f, 0.0556431f, -0.0516881f, -0.299758f, 0.559431f,
    -0.299758f, -0.0516881f, 0.0556431f, 0.023856f, -0.0071566f,
    -0.00188341f, 0.00134189f, 0.0f, -7.0626e-05f};
constexpr float F_G0[19] = {7.0626e-05f, 0.0f, -0.00134189f, -0.00188341f,
    0.0071566f, 0.023856f, -0.0556431f, -0.0516881f, 0.299758f, 0.559431f,
    0.299758f, -0.0516881f, -0.0556431f, 0.023856f, 0.0071566f,
    -0.00188341f, -0.00134189f, 0.0f, 7.0626e-05f};
constexpr float F_G1[13] = {-0.0017578125f, 0.0f, 0.022265625f, 0.046875f,
    -0.0482421875f, -0.296875f, 0.55546875f, -0.296875f, -0.0482421875f,
    0.046875f, 0.022265625f, 0.0f, -0.0017578125f};
}

__device__ __forceinline__ int symi(int k) {
    k = (k < 0) ? (-1 - k) : k;
    k = (k >= HS) ? (2 * HS - 1 - k) : k;
    return k;
}

__device__ __forceinline__ unsigned short f2bf(float f) {  // RNE bf16
    unsigned u = __float_as_uint(f);
    u += 0x7fffu + ((u >> 16) & 1u);
    return (unsigned short)(u >> 16);
}
__device__ __forceinline__ float bf2f(unsigned short h) {
    return __uint_as_float(((unsigned)h) << 16);
}

typedef __attribute__((ext_vector_type(8))) short short8;  // 8 bf16 (4 VGPR)
typedef __attribute__((ext_vector_type(4))) float f32x4;

// sbT layout: plane p = s*2 + ri (12 planes), [p][c 64][b 32][pos 784], bf16
#define PPOS 784
#define PS (BT * PPOS)

// ---- K0: transpose w_ll [c][h][w] -> wllT [h][w][c] (staged in d_out head)
__global__ __launch_bounds__(256) void k_wll_T(const float* __restrict__ wll,
                                               float* __restrict__ wllT) {
    __shared__ float tile[64][65];
    int pos0 = blockIdx.x * 64;
    int lp = threadIdx.x & 63, g = threadIdx.x >> 6;
#pragma unroll
    for (int r = 0; r < 16; ++r) {
        int cc = r * 4 + g;
        tile[cc][lp] = wll[cc * (HS * WS) + pos0 + lp];
    }
    __syncthreads();
#pragma unroll
    for (int r = 0; r < 16; ++r) {
        int pl = r * 4 + g;
        wllT[(pos0 + pl) * CH + lp] = tile[lp][pl];
    }
}

// ---- K1: forward row filters: x -> lo, hi (bf16)
// Batched load groups (7 independent loads in flight) to break the
// 1-load-per-iteration latency chain.
__global__ __launch_bounds__(256) void k_fwd_rows(const float* __restrict__ x,
                                                  unsigned short* __restrict__ lo,
                                                  unsigned short* __restrict__ hi) {
    int b = blockIdx.x / HS, h = blockIdx.x % HS;
    int strip = threadIdx.x >> 6, c = threadIdx.x & 63;
    int base = (b * HS + h) * WS * CH + c;
    const float* row = x + base;
    unsigned short* lop = lo + base;
    unsigned short* hip = hi + base;
    int w0s = strip * 14;
    float W[19];
#pragma unroll
    for (int t = 0; t < 19; ++t) W[t] = row[symi(w0s - 9 + t) * CH];
    for (int g = 0; g < 2; ++g) {
        float nW[7];
        int wg = w0s + g * 7;
#pragma unroll
        for (int u = 0; u < 7; ++u) nW[u] = row[symi(wg + u + 10) * CH];
#pragma unroll
        for (int u = 0; u < 7; ++u) {
            int w = wg + u;
            float aLo = 0.f, aHi = 0.f;
#pragma unroll
            for (int t = 0; t < 13; ++t) aLo += F_H0[t] * W[3 + t];
#pragma unroll
            for (int t = 0; t < 19; ++t) aHi += F_H1[t] * W[t];
            lop[w * CH] = f2bf(aLo);
            hip[w * CH] = f2bf(aHi);
#pragma unroll
            for (int t = 0; t < 18; ++t) W[t] = W[t + 1];
            W[18] = nW[u];
        }
    }
}

// ---- K2a: lo column filters, H-half split (blockIdx.y) -> xl + planes 0,1,10,11
__global__ __launch_bounds__(256) void k_cols_lo(
    const unsigned short* __restrict__ lo, const float* __restrict__ wllT,
    float* __restrict__ xl, unsigned short* __restrict__ sbT) {
    __shared__ float qT[4][64][15];  // 15.4 KB, pad 15 (gcd(15,32)=1)
    int hf = blockIdx.y;
    int b = blockIdx.x / WH, wp = blockIdx.x % WH;
    int w0 = 2 * wp, tid = threadIdx.x;
    int q = tid >> 6, c = tid & 63;
    int rp = q >> 1, jc = q & 1;
    const unsigned short* colbase = lo + (b * HS) * WS * CH + (w0 + jc) * CH + c;
    {
        int hstart = 2 * (hf * 14) + rp;
        float W[19];
#pragma unroll
        for (int t = 0; t < 19; ++t) W[t] = bf2f(colbase[symi(hstart - 9 + t) * (WS * CH)]);
        for (int g = 0; g < 2; ++g) {
            float nW0[7], nW1[7], nwll[7];
            int ii0 = g * 7;
#pragma unroll
            for (int u = 0; u < 7; ++u) {
                int h = hstart + 2 * (ii0 + u);
                nW0[u] = bf2f(colbase[symi(h + 10) * (WS * CH)]);
                nW1[u] = bf2f(colbase[symi(h + 11) * (WS * CH)]);
            }
#pragma unroll
            for (int u = 0; u < 7; ++u) {
                int h = hstart + 2 * (ii0 + u);
                nwll[u] = wllT[(h * WS + (w0 + jc)) * CH + c];
            }
#pragma unroll
            for (int u = 0; u < 7; ++u) {
                int ii = ii0 + u;
                int h = hstart + 2 * ii;
                float vll = 0.f, vlh = 0.f;
#pragma unroll
                for (int t = 0; t < 13; ++t) vll += F_H0[t] * W[3 + t];
#pragma unroll
                for (int t = 0; t < 19; ++t) vlh += F_H1[t] * W[t];
                xl[((b * HS + h) * WS + (w0 + jc)) * CH + c] = vll * nwll[u];
                qT[q][c][ii] = vlh;
#pragma unroll
                for (int t = 0; t < 17; ++t) W[t] = W[t + 2];
                W[17] = nW0[u];
                W[18] = nW1[u];
            }
        }
    }
    __syncthreads();
    // fused q2c + bf16 pack: j=q: 0:(a-d)->p0 1:(b+c)->p1 2:(a+d)->p10 3:(b-c)->p11
    int rowA = q & 1, rowB = 3 - (q & 1);
    float sgn = (q == 1 || q == 2) ? 1.f : -1.f;
    int p = (q < 2) ? q : q + 8;
    const float* qA = &qT[rowA][c][0];
    const float* qB = &qT[rowB][c][0];
    unsigned short* dst = sbT + ((p * 64 + c) * BT + b) * PPOS + wp * 28 + hf * 14;
#pragma unroll
    for (int g = 0; g < 7; ++g) {
        float2 a2 = *(const float2*)(qA + g * 2);
        float2 b2 = *(const float2*)(qB + g * 2);
        float v0 = (a2.x + sgn * b2.x) * ISQ2;
        float v1 = (a2.y + sgn * b2.y) * ISQ2;
        *(unsigned*)(dst + g * 2) = (unsigned)f2bf(v0) | ((unsigned)f2bf(v1) << 16);
    }
}

// ---- K2b: hi column filters, dual-filter single-read, H-half split
__global__ __launch_bounds__(256) void k_cols_hi(const unsigned short* __restrict__ hi,
                                                 unsigned short* __restrict__ sbT) {
    __shared__ float qT[2][4][64][15];  // 30.7 KB -> 5 blocks/CU
    int hf = blockIdx.y;
    int b = blockIdx.x / WH, wp = blockIdx.x % WH;
    int w0 = 2 * wp, tid = threadIdx.x;
    int q = tid >> 6, c = tid & 63;
    int rp = q >> 1, jc = q & 1;
    const unsigned short* colbase = hi + (b * HS) * WS * CH + (w0 + jc) * CH + c;
    {
        int hstart = 2 * (hf * 14) + rp;
        float W[19];
#pragma unroll
        for (int t = 0; t < 19; ++t) W[t] = bf2f(colbase[symi(hstart - 9 + t) * (WS * CH)]);
        for (int g = 0; g < 2; ++g) {
            float nW0[7], nW1[7];
            int ii0 = g * 7;
#pragma unroll
            for (int u = 0; u < 7; ++u) {
                int h = hstart + 2 * (ii0 + u);
                nW0[u] = bf2f(colbase[symi(h + 10) * (WS * CH)]);
                nW1[u] = bf2f(colbase[symi(h + 11) * (WS * CH)]);
            }
#pragma unroll
            for (int u = 0; u < 7; ++u) {
                int ii = ii0 + u;
                float vhl = 0.f, vhh = 0.f;
#pragma unroll
                for (int t = 0; t < 13; ++t) vhl += F_H0[t] * W[3 + t];
#pragma unroll
                for (int t = 0; t < 19; ++t) vhh += F_H1[t] * W[t];
                qT[0][q][c][ii] = vhl;
                qT[1][q][c][ii] = vhh;
#pragma unroll
                for (int t = 0; t < 17; ++t) W[t] = W[t + 2];
                W[17] = nW0[u];
                W[18] = nW1[u];
            }
        }
    }
    __syncthreads();
    int rowA = q & 1, rowB = 3 - (q & 1);
    float sgn = (q == 1 || q == 2) ? 1.f : -1.f;
#pragma unroll
    for (int src = 0; src < 2; ++src) {
        // src0 (hl): planes 4,5,6,7 (s2,s3); src1 (hh): planes 2,3,8,9 (s1,s4)
        int p = (src == 0) ? (4 + q) : ((q < 2) ? (2 + q) : (6 + q));
        const float* qA = &qT[src][rowA][c][0];
        const float* qB = &qT[src][rowB][c][0];
        unsigned short* dst = sbT + ((p * 64 + c) * BT + b) * PPOS + wp * 28 + hf * 14;
#pragma unroll
        for (int g = 0; g < 7; ++g) {
            float2 a2 = *(const float2*)(qA + g * 2);
            float2 b2 = *(const float2*)(qB + g * 2);
            float v0 = (a2.x + sgn * b2.x) * ISQ2;
            float v1 = (a2.y + sgn * b2.y) * ISQ2;
            *(unsigned*)(dst + g * 2) = (unsigned)f2bf(v0) | ((unsigned)f2bf(v1) << 16);
        }
    }
}

// ---- K3: MFMA channel mixing + fused c2q -> bf16 planes P[b][h][w][c]
__global__ __launch_bounds__(256) void k_mix(
    const unsigned short* __restrict__ sbT, const float* __restrict__ w1,
    const float* __restrict__ w2, const float* __restrict__ b1,
    const float* __restrict__ b2, unsigned short* __restrict__ P0,
    unsigned short* __restrict__ P1, unsigned short* __restrict__ P2) {
    __shared__ unsigned short l1a[4][16][36];
    __shared__ unsigned short l1b[4][16][36];
    int blk = blockIdx.x;
    int pr = blk / (BT * 7);
    int rem = blk % (BT * 7);
    int b = rem / 7;
    int chunk = rem % 7;
    int sa = (pr == 0) ? 0 : (pr == 1) ? 2 : 1;
    int sb = (pr == 0) ? 5 : (pr == 1) ? 3 : 4;
    unsigned short* Pd = (pr == 0) ? P0 : (pr == 1) ? P1 : P2;
    int tid = threadIdx.x;
    int lane = tid & 63;
    int wv = tid >> 6;
    int nb = __builtin_amdgcn_readfirstlane(wv);
    int quad = lane >> 4;
    int n = lane & 15;

    short8 B1r, B1i, B2r, B2i;
#pragma unroll
    for (int j = 0; j < 8; ++j) {
        int kk = quad * 8 + j;
        int riw = kk >> 4, dd = kk & 15;
        float v1r = w1[nb * 256 + dd * 16 + n];
        float v1i = w1[1024 + nb * 256 + dd * 16 + n];
        float v2r = w2[nb * 256 + dd * 16 + n];
        float v2i = w2[1024 + nb * 256 + dd * 16 + n];
        B1r[j] = (short)f2bf(riw ? -v1i : v1r);
        B1i[j] = (short)f2bf(riw ? v1r : v1i);
        B2r[j] = (short)f2bf(riw ? -v2i : v2r);
        B2i[j] = (short)f2bf(riw ? v2r : v2i);
    }
    float bias1r = b1[nb * 16 + n], bias1i = b1[64 + nb * 16 + n];
    float bias2r = b2[nb * 16 + n], bias2i = b2[64 + nb * 16 + n];

    int pbase = chunk * 112;
    for (int t = 0; t < 7; ++t) {
        int pos0 = pbase + t * 16;
        short8 A1a, A1b;
#pragma unroll
        for (int j = 0; j < 8; ++j) {
            int kk = quad * 8 + j;
            int rix = kk >> 4, dd = kk & 15;
            int cc = nb * 16 + dd;
            A1a[j] = (short)sbT[(((sa * 2 + rix) * 64 + cc) * BT + b) * PPOS + pos0 + n];
            A1b[j] = (short)sbT[(((sb * 2 + rix) * 64 + cc) * BT + b) * PPOS + pos0 + n];
        }
        f32x4 a1r = {bias1r, bias1r, bias1r, bias1r};
        f32x4 a1i = {bias1i, bias1i, bias1i, bias1i};
        f32x4 b1r_ = a1r, b1i_ = a1i;
        a1r = __builtin_amdgcn_mfma_f32_16x16x32_bf16(A1a, B1r, a1r, 0, 0, 0);
        a1i = __builtin_amdgcn_mfma_f32_16x16x32_bf16(A1a, B1i, a1i, 0, 0, 0);
        b1r_ = __builtin_amdgcn_mfma_f32_16x16x32_bf16(A1b, B1r, b1r_, 0, 0, 0);
        b1i_ = __builtin_amdgcn_mfma_f32_16x16x32_bf16(A1b, B1i, b1i_, 0, 0, 0);
#pragma unroll
        for (int r = 0; r < 4; ++r) {
            int pos = quad * 4 + r;
            l1a[wv][pos][n] = f2bf(fmaxf(a1r[r], 0.f));
            l1a[wv][pos][16 + n] = f2bf(fmaxf(a1i[r], 0.f));
            l1b[wv][pos][n] = f2bf(fmaxf(b1r_[r], 0.f));
            l1b[wv][pos][16 + n] = f2bf(fmaxf(b1i_[r], 0.f));
        }
        union { short8 s8; uint2 u2[2]; } a2a, a2b;
        const unsigned short* rowpa = &l1a[wv][n][0];
        const unsigned short* rowpb = &l1b[wv][n][0];
        a2a.u2[0] = *(const uint2*)(rowpa + quad * 8);
        a2a.u2[1] = *(const uint2*)(rowpa + quad * 8 + 4);
        a2b.u2[0] = *(const uint2*)(rowpb + quad * 8);
        a2b.u2[1] = *(const uint2*)(rowpb + quad * 8 + 4);
        f32x4 aAr = {bias2r, bias2r, bias2r, bias2r};
        f32x4 aAi = {bias2i, bias2i, bias2i, bias2i};
        f32x4 aBr = aAr, aBi = aAi;
        aAr = __builtin_amdgcn_mfma_f32_16x16x32_bf16(a2a.s8, B2r, aAr, 0, 0, 0);
        aAi = __builtin_amdgcn_mfma_f32_16x16x32_bf16(a2a.s8, B2i, aAi, 0, 0, 0);
        aBr = __builtin_amdgcn_mfma_f32_16x16x32_bf16(a2b.s8, B2r, aBr, 0, 0, 0);
        aBi = __builtin_amdgcn_mfma_f32_16x16x32_bf16(a2b.s8, B2i, aBi, 0, 0, 0);
#pragma unroll
        for (int r = 0; r < 4; ++r) {
            int pos_g = pos0 + quad * 4 + r;
            int wp = pos_g / 28, ii = pos_g - wp * 28;
            int o = ((b * HS + 2 * ii) * WS + 2 * wp) * CH + nb * 16 + n;
            Pd[o] = f2bf((aAr[r] + aBr[r]) * ISQ2);
            Pd[o + CH] = f2bf((aAi[r] + aBi[r]) * ISQ2);
            Pd[o + WS * CH] = f2bf((aAi[r] - aBi[r]) * ISQ2);
            Pd[o + WS * CH + CH] = f2bf((aBr[r] - aAr[r]) * ISQ2);
        }
    }
}

// ---- K4: inverse column pass, templated on mode (uniform blockIdx.z):
//   MODE=0: lo2 = G0col(xl fp32) + G1col(P0);  MODE=1: hi2 = G0col(P1) + G1col(P2)
// Batched load groups of 4 rows (8 loads in flight) to break the latency chain.
template <int MODE>
__device__ __forceinline__ void inv_cols_body(
    const float* __restrict__ xl, const unsigned short* __restrict__ P0,
    const unsigned short* __restrict__ P1, const unsigned short* __restrict__ P2,
    float* __restrict__ lo2, float* __restrict__ hi2) {
    int hf = blockIdx.y;
    int b = blockIdx.x / 14, wg = blockIdx.x % 14;
    int wl = threadIdx.x >> 6, c = threadIdx.x & 63;
    int w = wg * 4 + wl;
    int base = (b * HS) * WS * CH + w * CH + c;
    const int st = WS * CH;
    const unsigned short* Bp = (MODE == 0) ? P0 : P2;
    float* outp = (MODE == 0) ? lo2 : hi2;
    auto ldA = [&](int r) -> float {
        if (MODE == 0) return xl[base + r * st];
        return bf2f(P1[base + r * st]);
    };
    int h0 = hf * 28;
    float A[19], B[13];
#pragma unroll
    for (int t = 0; t < 19; ++t) A[t] = ldA(symi(h0 - 9 + t));
#pragma unroll
    for (int t = 0; t < 13; ++t) B[t] = bf2f(Bp[base + symi(h0 - 6 + t) * st]);
    for (int g = 0; g < 7; ++g) {
        float nA[4], nB[4];
        int hg = h0 + g * 4;
#pragma unroll
        for (int u = 0; u < 4; ++u) nA[u] = ldA(symi(hg + u + 10));
#pragma unroll
        for (int u = 0; u < 4; ++u) nB[u] = bf2f(Bp[base + symi(hg + u + 7) * st]);
#pragma unroll
        for (int u = 0; u < 4; ++u) {
            int h = hg + u;
            float acc = 0.f;
#pragma unroll
            for (int t = 0; t < 19; ++t) acc += F_G0[t] * A[t];
#pragma unroll
            for (int t = 0; t < 13; ++t) acc += F_G1[t] * B[t];
            outp[base + h * st] = acc;
#pragma unroll
            for (int t = 0; t < 18; ++t) A[t] = A[t + 1];
#pragma unroll
            for (int t = 0; t < 12; ++t) B[t] = B[t + 1];
            A[18] = nA[u];
            B[12] = nB[u];
        }
    }
}

__global__ __launch_bounds__(256) void k_inv_cols(
    const float* __restrict__ xl, const unsigned short* __restrict__ P0,
    const unsigned short* __restrict__ P1, const unsigned short* __restrict__ P2,
    float* __restrict__ lo2, float* __restrict__ hi2) {
    if (blockIdx.z == 0)
        inv_cols_body<0>(xl, P0, P1, P2, lo2, hi2);
    else
        inv_cols_body<1>(xl, P0, P1, P2, lo2, hi2);
}

// ---- K5: inverse row filters -> out (fp32), batched load groups of 7
__global__ __launch_bounds__(256) void k_inv_rows(const float* __restrict__ lo2,
                                                  const float* __restrict__ hi2,
                                                  float* __restrict__ out) {
    int b = blockIdx.x / HS, h = blockIdx.x % HS;
    int strip = threadIdx.x >> 6, c = threadIdx.x & 63;
    int base = (b * HS + h) * WS * CH + c;
    const float* rlo = lo2 + base;
    const float* rhi = hi2 + base;
    float* op = out + base;
    int w0s = strip * 14;
    float A[19], B[13];
#pragma unroll
    for (int t = 0; t < 19; ++t) A[t] = rlo[symi(w0s - 9 + t) * CH];
#pragma unroll
    for (int t = 0; t < 13; ++t) B[t] = rhi[symi(w0s - 6 + t) * CH];
    for (int g = 0; g < 2; ++g) {
        float nA[7], nB[7];
        int wgg = w0s + g * 7;
#pragma unroll
        for (int u = 0; u < 7; ++u) nA[u] = rlo[symi(wgg + u + 10) * CH];
#pragma unroll
        for (int u = 0; u < 7; ++u) nB[u] = rhi[symi(wgg + u + 7) * CH];
#pragma unroll
        for (int u = 0; u < 7; ++u) {
            int w = wgg + u;
            float acc = 0.f;
#pragma unroll
            for (int t = 0; t < 19; ++t) acc += F_G0[t] * A[t];
#pragma unroll
            for (int t = 0; t < 13; ++t) acc += F_G1[t] * B[t];
            op[w * CH] = acc;
#pragma unroll
            for (int t = 0; t < 18; ++t) A[t] = A[t + 1];
#pragma unroll
            for (int t = 0; t < 12; ++t) B[t] = B[t + 1];
            A[18] = nA[u];
            B[12] = nB[u];
        }
    }
}

extern "C" void kernel_launch(void* const* d_in, const int* in_sizes, int n_in,
                              void* d_out, int out_size, void* d_ws, size_t ws_size,
                              hipStream_t stream) {
    const float* x = (const float*)d_in[0];
    const float* w_ll = (const float*)d_in[1];
    const float* w1 = (const float*)d_in[2];
    const float* w2 = (const float*)d_in[3];
    const float* b1 = (const float*)d_in[4];
    const float* b2 = (const float*)d_in[5];
    float* out = (float*)d_out;

    // workspace map (float units). A = 6,422,528; SBf = 9,633,792.
    // xl | sbT(->lo2) | hi2 | lo_in | hi_in | P0 | P1 | P2  = 38.5M fl = 154 MB
    const size_t A = (size_t)BT * HS * WS * CH;
    const size_t SBf = (size_t)12 * 64 * BT * PPOS / 2;
    float* wsf = (float*)d_ws;
    float* xl = wsf;                                    // fp32, read by inv mode0
    unsigned short* sbT = (unsigned short*)(wsf + A);   // dead after mix
    float* lo2 = wsf + A;                               //   .. reuses sbT region
    float* hi2 = wsf + A + SBf;                         // fp32 (no alias w/ xl!)
    unsigned short* lo_in = (unsigned short*)(wsf + A + SBf + A);
    unsigned short* hi_in = lo_in + A;                  // bf16
    unsigned short* P0 = hi_in + A;                     // bf16
    unsigned short* P1 = P0 + A;
    unsigned short* P2 = P1 + A;

    float* wllT = out;  // staged in d_out head (overwritten by k_inv_rows)

    k_wll_T<<<49, 256, 0, stream>>>(w_ll, wllT);
    k_fwd_rows<<<BT * HS, 256, 0, stream>>>(x, lo_in, hi_in);
    k_cols_lo<<<dim3(BT * WH, 2), 256, 0, stream>>>(lo_in, wllT, xl, sbT);
    k_cols_hi<<<dim3(BT * WH, 2), 256, 0, stream>>>(hi_in, sbT);
    k_mix<<<3 * BT * 7, 256, 0, stream>>>(sbT, w1, w2, b1, b2, P0, P1, P2);
    k_inv_cols<<<dim3(BT * 14, 2, 2), 256, 0, stream>>>(xl, P0, P1, P2, lo2, hi2);
    k_inv_rows<<<BT * HS, 256, 0, stream>>>(lo2, hi2, out);
}

// Round 2
// 202.503 us; speedup vs baseline: 1.0732x; 1.0035x over previous
//
#include <hip/hip_runtime.h>

#define BT 32
#define CH 64
#define HS 56
#define WS 56
#define HH 28
#define WH 28

// ---------------- filter constants (exact reference values) ----------------
namespace {
constexpr float ISQ2 = 0.70710678118654752440f;
constexpr float F_H0[13] = {-0.0017578125f, 0.0f, 0.022265625f, -0.046875f,
    -0.0482421875f, 0.296875f, 0.55546875f, 0.296875f, -0.0482421875f,
    -0.046875f, 0.022265625f, 0.0f, -0.0017578125f};
constexpr float F_H1[19] = {-7.0626e-05f, 0.0f, 0.00134189f, -0.00188341f,
    -0.0071566f, 0.023856f, 0.0556431f, -0.0516881f, -0.299758f, 0.559431f,
    -0.299758f, -0.0516881f, 0.0556431f, 0.023856f, -0.0071566f,
    -0.00188341f, 0.00134189f, 0.0f, -7.0626e-05f};
constexpr float F_G0[19] = {7.0626e-05f, 0.0f, -0.00134189f, -0.00188341f,
    0.0071566f, 0.023856f, -0.0556431f, -0.0516881f, 0.299758f, 0.559431f,
    0.299758f, -0.0516881f, -0.0556431f, 0.023856f, 0.0071566f,
    -0.00188341f, -0.00134189f, 0.0f, 7.0626e-05f};
constexpr float F_G1[13] = {-0.0017578125f, 0.0f, 0.022265625f, 0.046875f,
    -0.0482421875f, -0.296875f, 0.55546875f, -0.296875f, -0.0482421875f,
    0.046875f, 0.022265625f, 0.0f, -0.0017578125f};
}

__device__ __forceinline__ int symi(int k) {
    k = (k < 0) ? (-1 - k) : k;
    k = (k >= HS) ? (2 * HS - 1 - k) : k;
    return k;
}

__device__ __forceinline__ unsigned short f2bf(float f) {  // RNE bf16
    unsigned u = __float_as_uint(f);
    u += 0x7fffu + ((u >> 16) & 1u);
    return (unsigned short)(u >> 16);
}
__device__ __forceinline__ float bf2f(unsigned short h) {
    return __uint_as_float(((unsigned)h) << 16);
}
// unpack 2 packed bf16 (channels c0, c0+1) from one dword
__device__ __forceinline__ float2 bfp2(unsigned u) {
    float2 r;
    r.x = __uint_as_float((u & 0xffffu) << 16);
    r.y = __uint_as_float(u & 0xffff0000u);
    return r;
}
__device__ __forceinline__ unsigned packbf(float a, float b) {
    return (unsigned)f2bf(a) | ((unsigned)f2bf(b) << 16);
}

typedef __attribute__((ext_vector_type(8))) short short8;  // 8 bf16 (4 VGPR)
typedef __attribute__((ext_vector_type(4))) float f32x4;

// sbT layout: plane p = s*2 + ri (12 planes), [p][c 64][b 32][pos 784], bf16
#define PPOS 784
#define PS (BT * PPOS)

// ---- K0: transpose w_ll [c][h][w] -> wllT [h][w][c] (staged in d_out head)
__global__ __launch_bounds__(256) void k_wll_T(const float* __restrict__ wll,
                                               float* __restrict__ wllT) {
    __shared__ float tile[64][65];
    int pos0 = blockIdx.x * 64;
    int lp = threadIdx.x & 63, g = threadIdx.x >> 6;
#pragma unroll
    for (int r = 0; r < 16; ++r) {
        int cc = r * 4 + g;
        tile[cc][lp] = wll[cc * (HS * WS) + pos0 + lp];
    }
    __syncthreads();
#pragma unroll
    for (int r = 0; r < 16; ++r) {
        int pl = r * 4 + g;
        wllT[(pos0 + pl) * CH + lp] = tile[lp][pl];
    }
}

// ---- K1: forward row filters: x -> lo, hi (bf16)
// 2 channels/thread (float2 loads, packed-uint stores), batched prefetch.
__global__ __launch_bounds__(256) void k_fwd_rows(const float* __restrict__ x,
                                                  unsigned short* __restrict__ lo,
                                                  unsigned short* __restrict__ hi) {
    int b = blockIdx.x / HS, h = blockIdx.x % HS;
    int strip = threadIdx.x >> 5;        // 0..7 strips of 7 w
    int c0 = (threadIdx.x & 31) * 2;
    int base = (b * HS + h) * WS * CH + c0;
    const float* row = x + base;
    unsigned short* lop = lo + base;
    unsigned short* hip = hi + base;
    int w0s = strip * 7;
    float Wa[19], Wb[19];
#pragma unroll
    for (int t = 0; t < 19; ++t) {
        float2 v = *(const float2*)(row + symi(w0s - 9 + t) * CH);
        Wa[t] = v.x; Wb[t] = v.y;
    }
    float2 nW[7];
#pragma unroll
    for (int u = 0; u < 7; ++u) nW[u] = *(const float2*)(row + symi(w0s + u + 10) * CH);
#pragma unroll
    for (int u = 0; u < 7; ++u) {
        int w = w0s + u;
        float aLo = 0.f, aHi = 0.f, bLo = 0.f, bHi = 0.f;
#pragma unroll
        for (int t = 0; t < 13; ++t) { aLo += F_H0[t] * Wa[3 + t]; bLo += F_H0[t] * Wb[3 + t]; }
#pragma unroll
        for (int t = 0; t < 19; ++t) { aHi += F_H1[t] * Wa[t]; bHi += F_H1[t] * Wb[t]; }
        *(unsigned*)(lop + w * CH) = packbf(aLo, bLo);
        *(unsigned*)(hip + w * CH) = packbf(aHi, bHi);
#pragma unroll
        for (int t = 0; t < 18; ++t) { Wa[t] = Wa[t + 1]; Wb[t] = Wb[t + 1]; }
        Wa[18] = nW[u].x; Wb[18] = nW[u].y;
    }
}

// ---- K2a: lo column filters, H-half split -> xl + planes 0,1,10,11
// 128 threads: q(4) x lane(32) x 2ch. uint loads of bf16 pairs.
__global__ __launch_bounds__(128) void k_cols_lo(
    const unsigned short* __restrict__ lo, const float* __restrict__ wllT,
    float* __restrict__ xl, unsigned short* __restrict__ sbT) {
    __shared__ float qT[4][64][15];  // 15.4 KB, pad 15 (gcd(15,32)=1)
    int hf = blockIdx.y;
    int b = blockIdx.x / WH, wp = blockIdx.x % WH;
    int w0 = 2 * wp, tid = threadIdx.x;
    int q = tid >> 5, l = tid & 31, c0 = l * 2;
    int rp = q >> 1, jc = q & 1;
    const unsigned short* colbase = lo + (b * HS) * WS * CH + (w0 + jc) * CH + c0;
    {
        int hstart = 2 * (hf * 14) + rp;
        float Wa[19], Wb[19];
#pragma unroll
        for (int t = 0; t < 19; ++t) {
            float2 v = bfp2(*(const unsigned*)(colbase + symi(hstart - 9 + t) * (WS * CH)));
            Wa[t] = v.x; Wb[t] = v.y;
        }
        for (int g = 0; g < 2; ++g) {
            unsigned nW0[7], nW1[7];
            float2 nwll[7];
            int ii0 = g * 7;
#pragma unroll
            for (int u = 0; u < 7; ++u) {
                int h = hstart + 2 * (ii0 + u);
                nW0[u] = *(const unsigned*)(colbase + symi(h + 10) * (WS * CH));
                nW1[u] = *(const unsigned*)(colbase + symi(h + 11) * (WS * CH));
            }
#pragma unroll
            for (int u = 0; u < 7; ++u) {
                int h = hstart + 2 * (ii0 + u);
                nwll[u] = *(const float2*)(wllT + (h * WS + (w0 + jc)) * CH + c0);
            }
#pragma unroll
            for (int u = 0; u < 7; ++u) {
                int ii = ii0 + u;
                int h = hstart + 2 * ii;
                float vlla = 0.f, vlha = 0.f, vllb = 0.f, vlhb = 0.f;
#pragma unroll
                for (int t = 0; t < 13; ++t) { vlla += F_H0[t] * Wa[3 + t]; vllb += F_H0[t] * Wb[3 + t]; }
#pragma unroll
                for (int t = 0; t < 19; ++t) { vlha += F_H1[t] * Wa[t]; vlhb += F_H1[t] * Wb[t]; }
                float2 ov; ov.x = vlla * nwll[u].x; ov.y = vllb * nwll[u].y;
                *(float2*)(xl + ((b * HS + h) * WS + (w0 + jc)) * CH + c0) = ov;
                qT[q][c0][ii] = vlha;
                qT[q][c0 + 1][ii] = vlhb;
#pragma unroll
                for (int t = 0; t < 17; ++t) { Wa[t] = Wa[t + 2]; Wb[t] = Wb[t + 2]; }
                float2 v0 = bfp2(nW0[u]), v1 = bfp2(nW1[u]);
                Wa[17] = v0.x; Wb[17] = v0.y;
                Wa[18] = v1.x; Wb[18] = v1.y;
            }
        }
    }
    __syncthreads();
    // fused q2c + bf16 pack: j=q: 0:(a-d)->p0 1:(b+c)->p1 2:(a+d)->p10 3:(b-c)->p11
    int rowA = q & 1, rowB = 3 - (q & 1);
    float sgn = (q == 1 || q == 2) ? 1.f : -1.f;
    int p = (q < 2) ? q : q + 8;
#pragma unroll
    for (int cc = 0; cc < 2; ++cc) {
        int c = c0 + cc;
        const float* qA = &qT[rowA][c][0];
        const float* qB = &qT[rowB][c][0];
        unsigned short* dst = sbT + ((p * 64 + c) * BT + b) * PPOS + wp * 28 + hf * 14;
#pragma unroll
        for (int g = 0; g < 7; ++g) {
            float2 a2 = *(const float2*)(qA + g * 2);
            float2 b2 = *(const float2*)(qB + g * 2);
            float v0 = (a2.x + sgn * b2.x) * ISQ2;
            float v1 = (a2.y + sgn * b2.y) * ISQ2;
            *(unsigned*)(dst + g * 2) = packbf(v0, v1);
        }
    }
}

// ---- K2b: hi column filters, dual-filter single-read, H-half split
__global__ __launch_bounds__(128) void k_cols_hi(const unsigned short* __restrict__ hi,
                                                 unsigned short* __restrict__ sbT) {
    __shared__ float qT[2][4][64][15];  // 30.7 KB
    int hf = blockIdx.y;
    int b = blockIdx.x / WH, wp = blockIdx.x % WH;
    int w0 = 2 * wp, tid = threadIdx.x;
    int q = tid >> 5, l = tid & 31, c0 = l * 2;
    int rp = q >> 1, jc = q & 1;
    const unsigned short* colbase = hi + (b * HS) * WS * CH + (w0 + jc) * CH + c0;
    {
        int hstart = 2 * (hf * 14) + rp;
        float Wa[19], Wb[19];
#pragma unroll
        for (int t = 0; t < 19; ++t) {
            float2 v = bfp2(*(const unsigned*)(colbase + symi(hstart - 9 + t) * (WS * CH)));
            Wa[t] = v.x; Wb[t] = v.y;
        }
        for (int g = 0; g < 2; ++g) {
            unsigned nW0[7], nW1[7];
            int ii0 = g * 7;
#pragma unroll
            for (int u = 0; u < 7; ++u) {
                int h = hstart + 2 * (ii0 + u);
                nW0[u] = *(const unsigned*)(colbase + symi(h + 10) * (WS * CH));
                nW1[u] = *(const unsigned*)(colbase + symi(h + 11) * (WS * CH));
            }
#pragma unroll
            for (int u = 0; u < 7; ++u) {
                int ii = ii0 + u;
                float vhla = 0.f, vhha = 0.f, vhlb = 0.f, vhhb = 0.f;
#pragma unroll
                for (int t = 0; t < 13; ++t) { vhla += F_H0[t] * Wa[3 + t]; vhlb += F_H0[t] * Wb[3 + t]; }
#pragma unroll
                for (int t = 0; t < 19; ++t) { vhha += F_H1[t] * Wa[t]; vhhb += F_H1[t] * Wb[t]; }
                qT[0][q][c0][ii] = vhla;
                qT[0][q][c0 + 1][ii] = vhlb;
                qT[1][q][c0][ii] = vhha;
                qT[1][q][c0 + 1][ii] = vhhb;
#pragma unroll
                for (int t = 0; t < 17; ++t) { Wa[t] = Wa[t + 2]; Wb[t] = Wb[t + 2]; }
                float2 v0 = bfp2(nW0[u]), v1 = bfp2(nW1[u]);
                Wa[17] = v0.x; Wb[17] = v0.y;
                Wa[18] = v1.x; Wb[18] = v1.y;
            }
        }
    }
    __syncthreads();
    int rowA = q & 1, rowB = 3 - (q & 1);
    float sgn = (q == 1 || q == 2) ? 1.f : -1.f;
#pragma unroll
    for (int src = 0; src < 2; ++src) {
        // src0 (hl): planes 4,5,6,7 (s2,s3); src1 (hh): planes 2,3,8,9 (s1,s4)
        int p = (src == 0) ? (4 + q) : ((q < 2) ? (2 + q) : (6 + q));
#pragma unroll
        for (int cc = 0; cc < 2; ++cc) {
            int c = c0 + cc;
            const float* qA = &qT[src][rowA][c][0];
            const float* qB = &qT[src][rowB][c][0];
            unsigned short* dst = sbT + ((p * 64 + c) * BT + b) * PPOS + wp * 28 + hf * 14;
#pragma unroll
            for (int g = 0; g < 7; ++g) {
                float2 a2 = *(const float2*)(qA + g * 2);
                float2 b2 = *(const float2*)(qB + g * 2);
                float v0 = (a2.x + sgn * b2.x) * ISQ2;
                float v1 = (a2.y + sgn * b2.y) * ISQ2;
                *(unsigned*)(dst + g * 2) = packbf(v0, v1);
            }
        }
    }
}

// ---- K3: MFMA channel mixing + fused c2q -> bf16 planes P[b][h][w][c]
__global__ __launch_bounds__(256) void k_mix(
    const unsigned short* __restrict__ sbT, const float* __restrict__ w1,
    const float* __restrict__ w2, const float* __restrict__ b1,
    const float* __restrict__ b2, unsigned short* __restrict__ P0,
    unsigned short* __restrict__ P1, unsigned short* __restrict__ P2) {
    __shared__ unsigned short l1a[4][16][36];
    __shared__ unsigned short l1b[4][16][36];
    int blk = blockIdx.x;
    int pr = blk / (BT * 7);
    int rem = blk % (BT * 7);
    int b = rem / 7;
    int chunk = rem % 7;
    int sa = (pr == 0) ? 0 : (pr == 1) ? 2 : 1;
    int sb = (pr == 0) ? 5 : (pr == 1) ? 3 : 4;
    unsigned short* Pd = (pr == 0) ? P0 : (pr == 1) ? P1 : P2;
    int tid = threadIdx.x;
    int lane = tid & 63;
    int wv = tid >> 6;
    int nb = __builtin_amdgcn_readfirstlane(wv);
    int quad = lane >> 4;
    int n = lane & 15;

    short8 B1r, B1i, B2r, B2i;
#pragma unroll
    for (int j = 0; j < 8; ++j) {
        int kk = quad * 8 + j;
        int riw = kk >> 4, dd = kk & 15;
        float v1r = w1[nb * 256 + dd * 16 + n];
        float v1i = w1[1024 + nb * 256 + dd * 16 + n];
        float v2r = w2[nb * 256 + dd * 16 + n];
        float v2i = w2[1024 + nb * 256 + dd * 16 + n];
        B1r[j] = (short)f2bf(riw ? -v1i : v1r);
        B1i[j] = (short)f2bf(riw ? v1r : v1i);
        B2r[j] = (short)f2bf(riw ? -v2i : v2r);
        B2i[j] = (short)f2bf(riw ? v2r : v2i);
    }
    float bias1r = b1[nb * 16 + n], bias1i = b1[64 + nb * 16 + n];
    float bias2r = b2[nb * 16 + n], bias2i = b2[64 + nb * 16 + n];

    int pbase = chunk * 112;
    for (int t = 0; t < 7; ++t) {
        int pos0 = pbase + t * 16;
        short8 A1a, A1b;
#pragma unroll
        for (int j = 0; j < 8; ++j) {
            int kk = quad * 8 + j;
            int rix = kk >> 4, dd = kk & 15;
            int cc = nb * 16 + dd;
            A1a[j] = (short)sbT[(((sa * 2 + rix) * 64 + cc) * BT + b) * PPOS + pos0 + n];
            A1b[j] = (short)sbT[(((sb * 2 + rix) * 64 + cc) * BT + b) * PPOS + pos0 + n];
        }
        f32x4 a1r = {bias1r, bias1r, bias1r, bias1r};
        f32x4 a1i = {bias1i, bias1i, bias1i, bias1i};
        f32x4 b1r_ = a1r, b1i_ = a1i;
        a1r = __builtin_amdgcn_mfma_f32_16x16x32_bf16(A1a, B1r, a1r, 0, 0, 0);
        a1i = __builtin_amdgcn_mfma_f32_16x16x32_bf16(A1a, B1i, a1i, 0, 0, 0);
        b1r_ = __builtin_amdgcn_mfma_f32_16x16x32_bf16(A1b, B1r, b1r_, 0, 0, 0);
        b1i_ = __builtin_amdgcn_mfma_f32_16x16x32_bf16(A1b, B1i, b1i_, 0, 0, 0);
#pragma unroll
        for (int r = 0; r < 4; ++r) {
            int pos = quad * 4 + r;
            l1a[wv][pos][n] = f2bf(fmaxf(a1r[r], 0.f));
            l1a[wv][pos][16 + n] = f2bf(fmaxf(a1i[r], 0.f));
            l1b[wv][pos][n] = f2bf(fmaxf(b1r_[r], 0.f));
            l1b[wv][pos][16 + n] = f2bf(fmaxf(b1i_[r], 0.f));
        }
        union { short8 s8; uint2 u2[2]; } a2a, a2b;
        const unsigned short* rowpa = &l1a[wv][n][0];
        const unsigned short* rowpb = &l1b[wv][n][0];
        a2a.u2[0] = *(const uint2*)(rowpa + quad * 8);
        a2a.u2[1] = *(const uint2*)(rowpa + quad * 8 + 4);
        a2b.u2[0] = *(const uint2*)(rowpb + quad * 8);
        a2b.u2[1] = *(const uint2*)(rowpb + quad * 8 + 4);
        f32x4 aAr = {bias2r, bias2r, bias2r, bias2r};
        f32x4 aAi = {bias2i, bias2i, bias2i, bias2i};
        f32x4 aBr = aAr, aBi = aAi;
        aAr = __builtin_amdgcn_mfma_f32_16x16x32_bf16(a2a.s8, B2r, aAr, 0, 0, 0);
        aAi = __builtin_amdgcn_mfma_f32_16x16x32_bf16(a2a.s8, B2i, aAi, 0, 0, 0);
        aBr = __builtin_amdgcn_mfma_f32_16x16x32_bf16(a2b.s8, B2r, aBr, 0, 0, 0);
        aBi = __builtin_amdgcn_mfma_f32_16x16x32_bf16(a2b.s8, B2i, aBi, 0, 0, 0);
#pragma unroll
        for (int r = 0; r < 4; ++r) {
            int pos_g = pos0 + quad * 4 + r;
            int wp = pos_g / 28, ii = pos_g - wp * 28;
            int o = ((b * HS + 2 * ii) * WS + 2 * wp) * CH + nb * 16 + n;
            Pd[o] = f2bf((aAr[r] + aBr[r]) * ISQ2);
            Pd[o + CH] = f2bf((aAi[r] + aBi[r]) * ISQ2);
            Pd[o + WS * CH] = f2bf((aAi[r] - aBi[r]) * ISQ2);
            Pd[o + WS * CH + CH] = f2bf((aBr[r] - aAr[r]) * ISQ2);
        }
    }
}

// ---- K4: inverse column pass, templated on mode (uniform blockIdx.z):
//   MODE=0: lo2 = G0col(xl fp32) + G1col(P0);  MODE=1: hi2 = G0col(P1) + G1col(P2)
// 2 channels/thread; 8 w per 256-thr block; batched load groups of 4 rows.
template <int MODE>
__device__ __forceinline__ void inv_cols_body(
    const float* __restrict__ xl, const unsigned short* __restrict__ P0,
    const unsigned short* __restrict__ P1, const unsigned short* __restrict__ P2,
    float* __restrict__ lo2, float* __restrict__ hi2) {
    int hf = blockIdx.y;
    int b = blockIdx.x / 7, wg = blockIdx.x % 7;
    int wl = threadIdx.x >> 5, l = threadIdx.x & 31;
    int c0 = l * 2;
    int w = wg * 8 + wl;
    int base = (b * HS) * WS * CH + w * CH + c0;
    const int st = WS * CH;
    const unsigned short* Bp = (MODE == 0) ? P0 : P2;
    float* outp = (MODE == 0) ? lo2 : hi2;
    auto ldA = [&](int r) -> float2 {
        if (MODE == 0) return *(const float2*)(xl + base + r * st);
        return bfp2(*(const unsigned*)(P1 + base + r * st));
    };
    auto ldB = [&](int r) -> float2 {
        return bfp2(*(const unsigned*)(Bp + base + r * st));
    };
    int h0 = hf * 28;
    float Aa[19], Ab[19], Ba[13], Bb[13];
#pragma unroll
    for (int t = 0; t < 19; ++t) { float2 v = ldA(symi(h0 - 9 + t)); Aa[t] = v.x; Ab[t] = v.y; }
#pragma unroll
    for (int t = 0; t < 13; ++t) { float2 v = ldB(symi(h0 - 6 + t)); Ba[t] = v.x; Bb[t] = v.y; }
    for (int g = 0; g < 7; ++g) {
        float2 nA[4], nB[4];
        int hg = h0 + g * 4;
#pragma unroll
        for (int u = 0; u < 4; ++u) nA[u] = ldA(symi(hg + u + 10));
#pragma unroll
        for (int u = 0; u < 4; ++u) nB[u] = ldB(symi(hg + u + 7));
#pragma unroll
        for (int u = 0; u < 4; ++u) {
            int h = hg + u;
            float acca = 0.f, accb = 0.f;
#pragma unroll
            for (int t = 0; t < 19; ++t) { acca += F_G0[t] * Aa[t]; accb += F_G0[t] * Ab[t]; }
#pragma unroll
            for (int t = 0; t < 13; ++t) { acca += F_G1[t] * Ba[t]; accb += F_G1[t] * Bb[t]; }
            float2 ov; ov.x = acca; ov.y = accb;
            *(float2*)(outp + base + h * st) = ov;
#pragma unroll
            for (int t = 0; t < 18; ++t) { Aa[t] = Aa[t + 1]; Ab[t] = Ab[t + 1]; }
#pragma unroll
            for (int t = 0; t < 12; ++t) { Ba[t] = Ba[t + 1]; Bb[t] = Bb[t + 1]; }
            Aa[18] = nA[u].x; Ab[18] = nA[u].y;
            Ba[12] = nB[u].x; Bb[12] = nB[u].y;
        }
    }
}

__global__ __launch_bounds__(256) void k_inv_cols(
    const float* __restrict__ xl, const unsigned short* __restrict__ P0,
    const unsigned short* __restrict__ P1, const unsigned short* __restrict__ P2,
    float* __restrict__ lo2, float* __restrict__ hi2) {
    if (blockIdx.z == 0)
        inv_cols_body<0>(xl, P0, P1, P2, lo2, hi2);
    else
        inv_cols_body<1>(xl, P0, P1, P2, lo2, hi2);
}

// ---- K5: inverse row filters -> out (fp32), 2 channels/thread, batched
__global__ __launch_bounds__(256) void k_inv_rows(const float* __restrict__ lo2,
                                                  const float* __restrict__ hi2,
                                                  float* __restrict__ out) {
    int b = blockIdx.x / HS, h = blockIdx.x % HS;
    int strip = threadIdx.x >> 5;        // 0..7 strips of 7 w
    int c0 = (threadIdx.x & 31) * 2;
    int base = (b * HS + h) * WS * CH + c0;
    const float* rlo = lo2 + base;
    const float* rhi = hi2 + base;
    float* op = out + base;
    int w0s = strip * 7;
    float Aa[19], Ab[19], Ba[13], Bb[13];
#pragma unroll
    for (int t = 0; t < 19; ++t) {
        float2 v = *(const float2*)(rlo + symi(w0s - 9 + t) * CH);
        Aa[t] = v.x; Ab[t] = v.y;
    }
#pragma unroll
    for (int t = 0; t < 13; ++t) {
        float2 v = *(const float2*)(rhi + symi(w0s - 6 + t) * CH);
        Ba[t] = v.x; Bb[t] = v.y;
    }
    float2 nA[7], nB[7];
#pragma unroll
    for (int u = 0; u < 7; ++u) nA[u] = *(const float2*)(rlo + symi(w0s + u + 10) * CH);
#pragma unroll
    for (int u = 0; u < 7; ++u) nB[u] = *(const float2*)(rhi + symi(w0s + u + 7) * CH);
#pragma unroll
    for (int u = 0; u < 7; ++u) {
        int w = w0s + u;
        float acca = 0.f, accb = 0.f;
#pragma unroll
        for (int t = 0; t < 19; ++t) { acca += F_G0[t] * Aa[t]; accb += F_G0[t] * Ab[t]; }
#pragma unroll
        for (int t = 0; t < 13; ++t) { acca += F_G1[t] * Ba[t]; accb += F_G1[t] * Bb[t]; }
        float2 ov; ov.x = acca; ov.y = accb;
        *(float2*)(op + w * CH) = ov;
#pragma unroll
        for (int t = 0; t < 18; ++t) { Aa[t] = Aa[t + 1]; Ab[t] = Ab[t + 1]; }
#pragma unroll
        for (int t = 0; t < 12; ++t) { Ba[t] = Ba[t + 1]; Bb[t] = Bb[t + 1]; }
        Aa[18] = nA[u].x; Ab[18] = nA[u].y;
        Ba[12] = nB[u].x; Bb[12] = nB[u].y;
    }
}

extern "C" void kernel_launch(void* const* d_in, const int* in_sizes, int n_in,
                              void* d_out, int out_size, void* d_ws, size_t ws_size,
                              hipStream_t stream) {
    const float* x = (const float*)d_in[0];
    const float* w_ll = (const float*)d_in[1];
    const float* w1 = (const float*)d_in[2];
    const float* w2 = (const float*)d_in[3];
    const float* b1 = (const float*)d_in[4];
    const float* b2 = (const float*)d_in[5];
    float* out = (float*)d_out;

    // workspace map (float units). A = 6,422,528; SBf = 9,633,792.
    // xl | sbT(->lo2) | hi2 | lo_in | hi_in | P0 | P1 | P2  = 38.5M fl = 154 MB
    const size_t A = (size_t)BT * HS * WS * CH;
    const size_t SBf = (size_t)12 * 64 * BT * PPOS / 2;
    float* wsf = (float*)d_ws;
    float* xl = wsf;                                    // fp32, read by inv mode0
    unsigned short* sbT = (unsigned short*)(wsf + A);   // dead after mix
    float* lo2 = wsf + A;                               //   .. reuses sbT region
    float* hi2 = wsf + A + SBf;                         // fp32 (no alias w/ xl!)
    unsigned short* lo_in = (unsigned short*)(wsf + A + SBf + A);
    unsigned short* hi_in = lo_in + A;                  // bf16
    unsigned short* P0 = hi_in + A;                     // bf16
    unsigned short* P1 = P0 + A;
    unsigned short* P2 = P1 + A;

    float* wllT = out;  // staged in d_out head (overwritten by k_inv_rows)

    k_wll_T<<<49, 256, 0, stream>>>(w_ll, wllT);
    k_fwd_rows<<<BT * HS, 256, 0, stream>>>(x, lo_in, hi_in);
    k_cols_lo<<<dim3(BT * WH, 2), 128, 0, stream>>>(lo_in, wllT, xl, sbT);
    k_cols_hi<<<dim3(BT * WH, 2), 128, 0, stream>>>(hi_in, sbT);
    k_mix<<<3 * BT * 7, 256, 0, stream>>>(sbT, w1, w2, b1, b2, P0, P1, P2);
    k_inv_cols<<<dim3(BT * 7, 2, 2), 256, 0, stream>>>(xl, P0, P1, P2, lo2, hi2);
    k_inv_rows<<<BT * HS, 256, 0, stream>>>(lo2, hi2, out);
}

// Round 3
// 180.068 us; speedup vs baseline: 1.2069x; 1.1246x over previous
//
#include <hip/hip_runtime.h>

#define BT 32
#define CH 64
#define HS 56
#define WS 56
#define HH 28
#define WH 28

// ---------------- filter constants (exact reference values) ----------------
namespace {
constexpr float ISQ2 = 0.70710678118654752440f;
constexpr float F_H0[13] = {-0.0017578125f, 0.0f, 0.022265625f, -0.046875f,
    -0.0482421875f, 0.296875f, 0.55546875f, 0.296875f, -0.0482421875f,
    -0.046875f, 0.022265625f, 0.0f, -0.0017578125f};
constexpr float F_H1[19] = {-7.0626e-05f, 0.0f, 0.00134189f, -0.00188341f,
    -0.0071566f, 0.023856f, 0.0556431f, -0.0516881f, -0.299758f, 0.559431f,
    -0.299758f, -0.0516881f, 0.0556431f, 0.023856f, -0.0071566f,
    -0.00188341f, 0.00134189f, 0.0f, -7.0626e-05f};
constexpr float F_G0[19] = {7.0626e-05f, 0.0f, -0.00134189f, -0.00188341f,
    0.0071566f, 0.023856f, -0.0556431f, -0.0516881f, 0.299758f, 0.559431f,
    0.299758f, -0.0516881f, -0.0556431f, 0.023856f, 0.0071566f,
    -0.00188341f, -0.00134189f, 0.0f, 7.0626e-05f};
constexpr float F_G1[13] = {-0.0017578125f, 0.0f, 0.022265625f, 0.046875f,
    -0.0482421875f, -0.296875f, 0.55546875f, -0.296875f, -0.0482421875f,
    0.046875f, 0.022265625f, 0.0f, -0.0017578125f};
}

__device__ __forceinline__ int symi(int k) {
    k = (k < 0) ? (-1 - k) : k;
    k = (k >= HS) ? (2 * HS - 1 - k) : k;
    return k;
}

__device__ __forceinline__ unsigned short f2bf(float f) {  // RNE bf16
    unsigned u = __float_as_uint(f);
    u += 0x7fffu + ((u >> 16) & 1u);
    return (unsigned short)(u >> 16);
}
__device__ __forceinline__ float bf2f(unsigned short h) {
    return __uint_as_float(((unsigned)h) << 16);
}
// unpack 2 packed bf16 (channels c0, c0+1) from one dword
__device__ __forceinline__ float2 bfp2(unsigned u) {
    float2 r;
    r.x = __uint_as_float((u & 0xffffu) << 16);
    r.y = __uint_as_float(u & 0xffff0000u);
    return r;
}
__device__ __forceinline__ unsigned packbf(float a, float b) {
    return (unsigned)f2bf(a) | ((unsigned)f2bf(b) << 16);
}

typedef __attribute__((ext_vector_type(8))) short short8;  // 8 bf16 (4 VGPR)
typedef __attribute__((ext_vector_type(4))) float f32x4;

// sbT layout (NEW): [p 12][b 32][pos 784][c 64], bf16.
// Writers emit full 128B lines (64ch contiguous); k_mix reads 16B/lane.
#define PPOS 784

// ---- K0: transpose w_ll [c][h][w] -> wllT [h][w][c] (staged in d_out head)
__global__ __launch_bounds__(256) void k_wll_T(const float* __restrict__ wll,
                                               float* __restrict__ wllT) {
    __shared__ float tile[64][65];
    int pos0 = blockIdx.x * 64;
    int lp = threadIdx.x & 63, g = threadIdx.x >> 6;
#pragma unroll
    for (int r = 0; r < 16; ++r) {
        int cc = r * 4 + g;
        tile[cc][lp] = wll[cc * (HS * WS) + pos0 + lp];
    }
    __syncthreads();
#pragma unroll
    for (int r = 0; r < 16; ++r) {
        int pl = r * 4 + g;
        wllT[(pos0 + pl) * CH + lp] = tile[lp][pl];
    }
}

// ---- K1: forward row filters: x -> lo, hi (bf16)
// 2 channels/thread (float2 loads, packed-uint stores), batched prefetch.
__global__ __launch_bounds__(256) void k_fwd_rows(const float* __restrict__ x,
                                                  unsigned short* __restrict__ lo,
                                                  unsigned short* __restrict__ hi) {
    int b = blockIdx.x / HS, h = blockIdx.x % HS;
    int strip = threadIdx.x >> 5;        // 0..7 strips of 7 w
    int c0 = (threadIdx.x & 31) * 2;
    int base = (b * HS + h) * WS * CH + c0;
    const float* row = x + base;
    unsigned short* lop = lo + base;
    unsigned short* hip = hi + base;
    int w0s = strip * 7;
    float Wa[19], Wb[19];
#pragma unroll
    for (int t = 0; t < 19; ++t) {
        float2 v = *(const float2*)(row + symi(w0s - 9 + t) * CH);
        Wa[t] = v.x; Wb[t] = v.y;
    }
    float2 nW[7];
#pragma unroll
    for (int u = 0; u < 7; ++u) nW[u] = *(const float2*)(row + symi(w0s + u + 10) * CH);
#pragma unroll
    for (int u = 0; u < 7; ++u) {
        int w = w0s + u;
        float aLo = 0.f, aHi = 0.f, bLo = 0.f, bHi = 0.f;
#pragma unroll
        for (int t = 0; t < 13; ++t) { aLo += F_H0[t] * Wa[3 + t]; bLo += F_H0[t] * Wb[3 + t]; }
#pragma unroll
        for (int t = 0; t < 19; ++t) { aHi += F_H1[t] * Wa[t]; bHi += F_H1[t] * Wb[t]; }
        *(unsigned*)(lop + w * CH) = packbf(aLo, bLo);
        *(unsigned*)(hip + w * CH) = packbf(aHi, bHi);
#pragma unroll
        for (int t = 0; t < 18; ++t) { Wa[t] = Wa[t + 1]; Wb[t] = Wb[t + 1]; }
        Wa[18] = nW[u].x; Wb[18] = nW[u].y;
    }
}

// ---- K2a: lo column filters, H-half split -> xl + planes 0,1,10,11
// 256 threads: q(4) x c(64). Filter phase 1ch/lane; pack phase 8 groups,
// full-line uint stores into [p][b][pos][c] layout.
__global__ __launch_bounds__(256) void k_cols_lo(
    const unsigned short* __restrict__ lo, const float* __restrict__ wllT,
    float* __restrict__ xl, unsigned short* __restrict__ sbT) {
    __shared__ float qT[4][64][15];  // 15.4 KB, pad 15 (gcd(15,32)=1)
    int hf = blockIdx.y;
    int b = blockIdx.x / WH, wp = blockIdx.x % WH;
    int w0 = 2 * wp, tid = threadIdx.x;
    int q = tid >> 6, c = tid & 63;
    int rp = q >> 1, jc = q & 1;
    const unsigned short* colbase = lo + (b * HS) * WS * CH + (w0 + jc) * CH + c;
    {
        int hstart = 2 * (hf * 14) + rp;
        float W[19];
#pragma unroll
        for (int t = 0; t < 19; ++t) W[t] = bf2f(colbase[symi(hstart - 9 + t) * (WS * CH)]);
        for (int g = 0; g < 2; ++g) {
            float nW0[7], nW1[7], nwll[7];
            int ii0 = g * 7;
#pragma unroll
            for (int u = 0; u < 7; ++u) {
                int h = hstart + 2 * (ii0 + u);
                nW0[u] = bf2f(colbase[symi(h + 10) * (WS * CH)]);
                nW1[u] = bf2f(colbase[symi(h + 11) * (WS * CH)]);
            }
#pragma unroll
            for (int u = 0; u < 7; ++u) {
                int h = hstart + 2 * (ii0 + u);
                nwll[u] = wllT[(h * WS + (w0 + jc)) * CH + c];
            }
#pragma unroll
            for (int u = 0; u < 7; ++u) {
                int ii = ii0 + u;
                int h = hstart + 2 * ii;
                float vll = 0.f, vlh = 0.f;
#pragma unroll
                for (int t = 0; t < 13; ++t) vll += F_H0[t] * W[3 + t];
#pragma unroll
                for (int t = 0; t < 19; ++t) vlh += F_H1[t] * W[t];
                xl[((b * HS + h) * WS + (w0 + jc)) * CH + c] = vll * nwll[u];
                qT[q][c][ii] = vlh;
#pragma unroll
                for (int t = 0; t < 17; ++t) W[t] = W[t + 2];
                W[17] = nW0[u];
                W[18] = nW1[u];
            }
        }
    }
    __syncthreads();
    // fused q2c + bf16 pack: role 0:(a-d)->p0 1:(b+c)->p1 2:(a+d)->p10 3:(b-c)->p11
    {
        int qq = tid >> 5;                 // 0..7
        int role = qq & 3, half = qq >> 2; // ii-half 0..6 / 7..13
        int c0 = (tid & 31) * 2;
        int rowA = role & 1, rowB = 3 - (role & 1);
        float sgn = (role == 1 || role == 2) ? 1.f : -1.f;
        int p = (role < 2) ? role : role + 8;
        const float* qA0 = &qT[rowA][c0][0];
        const float* qA1 = &qT[rowA][c0 + 1][0];
        const float* qB0 = &qT[rowB][c0][0];
        const float* qB1 = &qT[rowB][c0 + 1][0];
        unsigned short* dst = sbT + ((p * BT + b) * PPOS + wp * 28 + hf * 14) * CH + c0;
#pragma unroll
        for (int g = 0; g < 7; ++g) {
            int ii = half * 7 + g;
            float v0 = (qA0[ii] + sgn * qB0[ii]) * ISQ2;
            float v1 = (qA1[ii] + sgn * qB1[ii]) * ISQ2;
            *(unsigned*)(dst + ii * CH) = packbf(v0, v1);
        }
    }
}

// ---- K2b: hi column filters, dual-filter single-read, H-half split
__global__ __launch_bounds__(256) void k_cols_hi(const unsigned short* __restrict__ hi,
                                                 unsigned short* __restrict__ sbT) {
    __shared__ float qT[2][4][64][15];  // 30.7 KB -> 5 blocks/CU @256thr = 20 waves
    int hf = blockIdx.y;
    int b = blockIdx.x / WH, wp = blockIdx.x % WH;
    int w0 = 2 * wp, tid = threadIdx.x;
    int q = tid >> 6, c = tid & 63;
    int rp = q >> 1, jc = q & 1;
    const unsigned short* colbase = hi + (b * HS) * WS * CH + (w0 + jc) * CH + c;
    {
        int hstart = 2 * (hf * 14) + rp;
        float W[19];
#pragma unroll
        for (int t = 0; t < 19; ++t) W[t] = bf2f(colbase[symi(hstart - 9 + t) * (WS * CH)]);
        for (int g = 0; g < 2; ++g) {
            float nW0[7], nW1[7];
            int ii0 = g * 7;
#pragma unroll
            for (int u = 0; u < 7; ++u) {
                int h = hstart + 2 * (ii0 + u);
                nW0[u] = bf2f(colbase[symi(h + 10) * (WS * CH)]);
                nW1[u] = bf2f(colbase[symi(h + 11) * (WS * CH)]);
            }
#pragma unroll
            for (int u = 0; u < 7; ++u) {
                int ii = ii0 + u;
                float vhl = 0.f, vhh = 0.f;
#pragma unroll
                for (int t = 0; t < 13; ++t) vhl += F_H0[t] * W[3 + t];
#pragma unroll
                for (int t = 0; t < 19; ++t) vhh += F_H1[t] * W[t];
                qT[0][q][c][ii] = vhl;
                qT[1][q][c][ii] = vhh;
#pragma unroll
                for (int t = 0; t < 17; ++t) W[t] = W[t + 2];
                W[17] = nW0[u];
                W[18] = nW1[u];
            }
        }
    }
    __syncthreads();
    {
        int qq = tid >> 5;                 // 0..7
        int role = qq & 3, half = qq >> 2;
        int c0 = (tid & 31) * 2;
        int rowA = role & 1, rowB = 3 - (role & 1);
        float sgn = (role == 1 || role == 2) ? 1.f : -1.f;
#pragma unroll
        for (int src = 0; src < 2; ++src) {
            // src0 (hl): planes 4,5,6,7 (s2,s3); src1 (hh): planes 2,3,8,9 (s1,s4)
            int p = (src == 0) ? (4 + role) : ((role < 2) ? (2 + role) : (6 + role));
            const float* qA0 = &qT[src][rowA][c0][0];
            const float* qA1 = &qT[src][rowA][c0 + 1][0];
            const float* qB0 = &qT[src][rowB][c0][0];
            const float* qB1 = &qT[src][rowB][c0 + 1][0];
            unsigned short* dst = sbT + ((p * BT + b) * PPOS + wp * 28 + hf * 14) * CH + c0;
#pragma unroll
            for (int g = 0; g < 7; ++g) {
                int ii = half * 7 + g;
                float v0 = (qA0[ii] + sgn * qB0[ii]) * ISQ2;
                float v1 = (qA1[ii] + sgn * qB1[ii]) * ISQ2;
                *(unsigned*)(dst + ii * CH) = packbf(v0, v1);
            }
        }
    }
}

// ---- K3: MFMA channel mixing + fused c2q -> bf16 planes P[b][h][w][c]
// sbT [p][b][pos][c] layout: each A-fragment = one 16B dwordx4 load per lane.
__global__ __launch_bounds__(256) void k_mix(
    const unsigned short* __restrict__ sbT, const float* __restrict__ w1,
    const float* __restrict__ w2, const float* __restrict__ b1,
    const float* __restrict__ b2, unsigned short* __restrict__ P0,
    unsigned short* __restrict__ P1, unsigned short* __restrict__ P2) {
    __shared__ unsigned short l1a[4][16][36];
    __shared__ unsigned short l1b[4][16][36];
    int blk = blockIdx.x;
    int pr = blk / (BT * 7);
    int rem = blk % (BT * 7);
    int b = rem / 7;
    int chunk = rem % 7;
    int sa = (pr == 0) ? 0 : (pr == 1) ? 2 : 1;
    int sb = (pr == 0) ? 5 : (pr == 1) ? 3 : 4;
    unsigned short* Pd = (pr == 0) ? P0 : (pr == 1) ? P1 : P2;
    int tid = threadIdx.x;
    int lane = tid & 63;
    int wv = tid >> 6;
    int nb = __builtin_amdgcn_readfirstlane(wv);
    int quad = lane >> 4;
    int n = lane & 15;

    short8 B1r, B1i, B2r, B2i;
#pragma unroll
    for (int j = 0; j < 8; ++j) {
        int kk = quad * 8 + j;
        int riw = kk >> 4, dd = kk & 15;
        float v1r = w1[nb * 256 + dd * 16 + n];
        float v1i = w1[1024 + nb * 256 + dd * 16 + n];
        float v2r = w2[nb * 256 + dd * 16 + n];
        float v2i = w2[1024 + nb * 256 + dd * 16 + n];
        B1r[j] = (short)f2bf(riw ? -v1i : v1r);
        B1i[j] = (short)f2bf(riw ? v1r : v1i);
        B2r[j] = (short)f2bf(riw ? -v2i : v2r);
        B2i[j] = (short)f2bf(riw ? v2r : v2i);
    }
    float bias1r = b1[nb * 16 + n], bias1i = b1[64 + nb * 16 + n];
    float bias2r = b2[nb * 16 + n], bias2i = b2[64 + nb * 16 + n];

    // A-fragment base pointers: lane reads 8 consecutive channels (16B) at
    // plane = s*2 + (quad>>1), pos = pos0 + n, c = nb*16 + (quad&1)*8.
    int rix = quad >> 1, dlo = (quad & 1) * 8;
    const unsigned short* pAa =
        sbT + (((sa * 2 + rix) * BT + b) * PPOS + n) * CH + nb * 16 + dlo;
    const unsigned short* pAb =
        sbT + (((sb * 2 + rix) * BT + b) * PPOS + n) * CH + nb * 16 + dlo;

    int pbase = chunk * 112;
    for (int t = 0; t < 7; ++t) {
        int pos0 = pbase + t * 16;
        short8 A1a = *(const short8*)(pAa + pos0 * CH);
        short8 A1b = *(const short8*)(pAb + pos0 * CH);
        f32x4 a1r = {bias1r, bias1r, bias1r, bias1r};
        f32x4 a1i = {bias1i, bias1i, bias1i, bias1i};
        f32x4 b1r_ = a1r, b1i_ = a1i;
        a1r = __builtin_amdgcn_mfma_f32_16x16x32_bf16(A1a, B1r, a1r, 0, 0, 0);
        a1i = __builtin_amdgcn_mfma_f32_16x16x32_bf16(A1a, B1i, a1i, 0, 0, 0);
        b1r_ = __builtin_amdgcn_mfma_f32_16x16x32_bf16(A1b, B1r, b1r_, 0, 0, 0);
        b1i_ = __builtin_amdgcn_mfma_f32_16x16x32_bf16(A1b, B1i, b1i_, 0, 0, 0);
#pragma unroll
        for (int r = 0; r < 4; ++r) {
            int pos = quad * 4 + r;
            l1a[wv][pos][n] = f2bf(fmaxf(a1r[r], 0.f));
            l1a[wv][pos][16 + n] = f2bf(fmaxf(a1i[r], 0.f));
            l1b[wv][pos][n] = f2bf(fmaxf(b1r_[r], 0.f));
            l1b[wv][pos][16 + n] = f2bf(fmaxf(b1i_[r], 0.f));
        }
        union { short8 s8; uint2 u2[2]; } a2a, a2b;
        const unsigned short* rowpa = &l1a[wv][n][0];
        const unsigned short* rowpb = &l1b[wv][n][0];
        a2a.u2[0] = *(const uint2*)(rowpa + quad * 8);
        a2a.u2[1] = *(const uint2*)(rowpa + quad * 8 + 4);
        a2b.u2[0] = *(const uint2*)(rowpb + quad * 8);
        a2b.u2[1] = *(const uint2*)(rowpb + quad * 8 + 4);
        f32x4 aAr = {bias2r, bias2r, bias2r, bias2r};
        f32x4 aAi = {bias2i, bias2i, bias2i, bias2i};
        f32x4 aBr = aAr, aBi = aAi;
        aAr = __builtin_amdgcn_mfma_f32_16x16x32_bf16(a2a.s8, B2r, aAr, 0, 0, 0);
        aAi = __builtin_amdgcn_mfma_f32_16x16x32_bf16(a2a.s8, B2i, aAi, 0, 0, 0);
        aBr = __builtin_amdgcn_mfma_f32_16x16x32_bf16(a2b.s8, B2r, aBr, 0, 0, 0);
        aBi = __builtin_amdgcn_mfma_f32_16x16x32_bf16(a2b.s8, B2i, aBi, 0, 0, 0);
#pragma unroll
        for (int r = 0; r < 4; ++r) {
            int pos_g = pos0 + quad * 4 + r;
            int wp = pos_g / 28, ii = pos_g - wp * 28;
            int o = ((b * HS + 2 * ii) * WS + 2 * wp) * CH + nb * 16 + n;
            Pd[o] = f2bf((aAr[r] + aBr[r]) * ISQ2);
            Pd[o + CH] = f2bf((aAi[r] + aBi[r]) * ISQ2);
            Pd[o + WS * CH] = f2bf((aAi[r] - aBi[r]) * ISQ2);
            Pd[o + WS * CH + CH] = f2bf((aBr[r] - aAr[r]) * ISQ2);
        }
    }
}

// ---- K4: inverse column pass, templated on mode (uniform blockIdx.z):
//   MODE=0: lo2 = G0col(xl fp32) + G1col(P0);  MODE=1: hi2 = G0col(P1) + G1col(P2)
// 2 channels/thread; 8 w per 256-thr block; batched load groups of 4 rows.
template <int MODE>
__device__ __forceinline__ void inv_cols_body(
    const float* __restrict__ xl, const unsigned short* __restrict__ P0,
    const unsigned short* __restrict__ P1, const unsigned short* __restrict__ P2,
    float* __restrict__ lo2, float* __restrict__ hi2) {
    int hf = blockIdx.y;
    int b = blockIdx.x / 7, wg = blockIdx.x % 7;
    int wl = threadIdx.x >> 5, l = threadIdx.x & 31;
    int c0 = l * 2;
    int w = wg * 8 + wl;
    int base = (b * HS) * WS * CH + w * CH + c0;
    const int st = WS * CH;
    const unsigned short* Bp = (MODE == 0) ? P0 : P2;
    float* outp = (MODE == 0) ? lo2 : hi2;
    auto ldA = [&](int r) -> float2 {
        if (MODE == 0) return *(const float2*)(xl + base + r * st);
        return bfp2(*(const unsigned*)(P1 + base + r * st));
    };
    auto ldB = [&](int r) -> float2 {
        return bfp2(*(const unsigned*)(Bp + base + r * st));
    };
    int h0 = hf * 28;
    float Aa[19], Ab[19], Ba[13], Bb[13];
#pragma unroll
    for (int t = 0; t < 19; ++t) { float2 v = ldA(symi(h0 - 9 + t)); Aa[t] = v.x; Ab[t] = v.y; }
#pragma unroll
    for (int t = 0; t < 13; ++t) { float2 v = ldB(symi(h0 - 6 + t)); Ba[t] = v.x; Bb[t] = v.y; }
    for (int g = 0; g < 7; ++g) {
        float2 nA[4], nB[4];
        int hg = h0 + g * 4;
#pragma unroll
        for (int u = 0; u < 4; ++u) nA[u] = ldA(symi(hg + u + 10));
#pragma unroll
        for (int u = 0; u < 4; ++u) nB[u] = ldB(symi(hg + u + 7));
#pragma unroll
        for (int u = 0; u < 4; ++u) {
            int h = hg + u;
            float acca = 0.f, accb = 0.f;
#pragma unroll
            for (int t = 0; t < 19; ++t) { acca += F_G0[t] * Aa[t]; accb += F_G0[t] * Ab[t]; }
#pragma unroll
            for (int t = 0; t < 13; ++t) { acca += F_G1[t] * Ba[t]; accb += F_G1[t] * Bb[t]; }
            float2 ov; ov.x = acca; ov.y = accb;
            *(float2*)(outp + base + h * st) = ov;
#pragma unroll
            for (int t = 0; t < 18; ++t) { Aa[t] = Aa[t + 1]; Ab[t] = Ab[t + 1]; }
#pragma unroll
            for (int t = 0; t < 12; ++t) { Ba[t] = Ba[t + 1]; Bb[t] = Bb[t + 1]; }
            Aa[18] = nA[u].x; Ab[18] = nA[u].y;
            Ba[12] = nB[u].x; Bb[12] = nB[u].y;
        }
    }
}

__global__ __launch_bounds__(256) void k_inv_cols(
    const float* __restrict__ xl, const unsigned short* __restrict__ P0,
    const unsigned short* __restrict__ P1, const unsigned short* __restrict__ P2,
    float* __restrict__ lo2, float* __restrict__ hi2) {
    if (blockIdx.z == 0)
        inv_cols_body<0>(xl, P0, P1, P2, lo2, hi2);
    else
        inv_cols_body<1>(xl, P0, P1, P2, lo2, hi2);
}

// ---- K5: inverse row filters -> out (fp32), 2 channels/thread, batched
__global__ __launch_bounds__(256) void k_inv_rows(const float* __restrict__ lo2,
                                                  const float* __restrict__ hi2,
                                                  float* __restrict__ out) {
    int b = blockIdx.x / HS, h = blockIdx.x % HS;
    int strip = threadIdx.x >> 5;        // 0..7 strips of 7 w
    int c0 = (threadIdx.x & 31) * 2;
    int base = (b * HS + h) * WS * CH + c0;
    const float* rlo = lo2 + base;
    const float* rhi = hi2 + base;
    float* op = out + base;
    int w0s = strip * 7;
    float Aa[19], Ab[19], Ba[13], Bb[13];
#pragma unroll
    for (int t = 0; t < 19; ++t) {
        float2 v = *(const float2*)(rlo + symi(w0s - 9 + t) * CH);
        Aa[t] = v.x; Ab[t] = v.y;
    }
#pragma unroll
    for (int t = 0; t < 13; ++t) {
        float2 v = *(const float2*)(rhi + symi(w0s - 6 + t) * CH);
        Ba[t] = v.x; Bb[t] = v.y;
    }
    float2 nA[7], nB[7];
#pragma unroll
    for (int u = 0; u < 7; ++u) nA[u] = *(const float2*)(rlo + symi(w0s + u + 10) * CH);
#pragma unroll
    for (int u = 0; u < 7; ++u) nB[u] = *(const float2*)(rhi + symi(w0s + u + 7) * CH);
#pragma unroll
    for (int u = 0; u < 7; ++u) {
        int w = w0s + u;
        float acca = 0.f, accb = 0.f;
#pragma unroll
        for (int t = 0; t < 19; ++t) { acca += F_G0[t] * Aa[t]; accb += F_G0[t] * Ab[t]; }
#pragma unroll
        for (int t = 0; t < 13; ++t) { acca += F_G1[t] * Ba[t]; accb += F_G1[t] * Bb[t]; }
        float2 ov; ov.x = acca; ov.y = accb;
        *(float2*)(op + w * CH) = ov;
#pragma unroll
        for (int t = 0; t < 18; ++t) { Aa[t] = Aa[t + 1]; Ab[t] = Ab[t + 1]; }
#pragma unroll
        for (int t = 0; t < 12; ++t) { Ba[t] = Ba[t + 1]; Bb[t] = Bb[t + 1]; }
        Aa[18] = nA[u].x; Ab[18] = nA[u].y;
        Ba[12] = nB[u].x; Bb[12] = nB[u].y;
    }
}

extern "C" void kernel_launch(void* const* d_in, const int* in_sizes, int n_in,
                              void* d_out, int out_size, void* d_ws, size_t ws_size,
                              hipStream_t stream) {
    const float* x = (const float*)d_in[0];
    const float* w_ll = (const float*)d_in[1];
    const float* w1 = (const float*)d_in[2];
    const float* w2 = (const float*)d_in[3];
    const float* b1 = (const float*)d_in[4];
    const float* b2 = (const float*)d_in[5];
    float* out = (float*)d_out;

    // workspace map (float units). A = 6,422,528; SBf = 9,633,792.
    // xl | sbT(->lo2) | hi2 | lo_in | hi_in | P0 | P1 | P2  = 38.5M fl = 154 MB
    const size_t A = (size_t)BT * HS * WS * CH;
    const size_t SBf = (size_t)12 * 64 * BT * PPOS / 2;
    float* wsf = (float*)d_ws;
    float* xl = wsf;                                    // fp32, read by inv mode0
    unsigned short* sbT = (unsigned short*)(wsf + A);   // dead after mix
    float* lo2 = wsf + A;                               //   .. reuses sbT region
    float* hi2 = wsf + A + SBf;                         // fp32 (no alias w/ xl!)
    unsigned short* lo_in = (unsigned short*)(wsf + A + SBf + A);
    unsigned short* hi_in = lo_in + A;                  // bf16
    unsigned short* P0 = hi_in + A;                     // bf16
    unsigned short* P1 = P0 + A;
    unsigned short* P2 = P1 + A;

    float* wllT = out;  // staged in d_out head (overwritten by k_inv_rows)

    k_wll_T<<<49, 256, 0, stream>>>(w_ll, wllT);
    k_fwd_rows<<<BT * HS, 256, 0, stream>>>(x, lo_in, hi_in);
    k_cols_lo<<<dim3(BT * WH, 2), 256, 0, stream>>>(lo_in, wllT, xl, sbT);
    k_cols_hi<<<dim3(BT * WH, 2), 256, 0, stream>>>(hi_in, sbT);
    k_mix<<<3 * BT * 7, 256, 0, stream>>>(sbT, w1, w2, b1, b2, P0, P1, P2);
    k_inv_cols<<<dim3(BT * 7, 2, 2), 256, 0, stream>>>(xl, P0, P1, P2, lo2, hi2);
    k_inv_rows<<<BT * HS, 256, 0, stream>>>(lo2, hi2, out);
}